// Round 1
// baseline (294.607 us; speedup 1.0000x reference)
//
#include <hip/hip_runtime.h>
#include <math.h>

#define BB   64
#define TT   1000
#define DEC  1024
#define ENCD 512
#define ATT  128
#define FILT 32
#define KSZ  31
#define PADW 15
#define BT   64   // t-tile per block
#define KC   32   // K chunk

// ---------------- K1: query = decoder_hidden @ query_w^T  (64 x 128) ----------
__global__ __launch_bounds__(128) void k_query(const float* __restrict__ dh,
                                               const float* __restrict__ qw,
                                               float* __restrict__ q) {
    int b = blockIdx.x, a = threadIdx.x;
    const float* dhb = dh + b * DEC;
    const float* qwa = qw + a * DEC;
    float s = 0.f;
    #pragma unroll 4
    for (int k = 0; k < DEC; k += 4) {
        float4 x = *(const float4*)&dhb[k];
        float4 w = *(const float4*)&qwa[k];
        s += x.x * w.x + x.y * w.y + x.z * w.z + x.w * w.w;
    }
    q[b * ATT + a] = s;
}

// ---------------- K3: fused conv + loc_proj + keys GEMM + tanh + v-dot --------
union SMem {
    struct {
        float x[2][BT + KSZ - 1];     // 2 x 94
        float cw[FILT * 2 * KSZ];     // 1984
        float feat[FILT][BT];         // 32 x 64
    } conv;
    struct {
        float a[KC][BT + 4];          // enc tile, transposed  (k, t)
        float b[KC][ATT + 4];         // key_w tile, transposed (k, a)
    } gemm;
};

__global__ __launch_bounds__(256) void k_energies(
    const float* __restrict__ enc, const float* __restrict__ pw,
    const float* __restrict__ pwc, const float* __restrict__ cw,
    const float* __restrict__ lpw, const float* __restrict__ kw,
    const float* __restrict__ vw, const float* __restrict__ q,
    float* __restrict__ energ)
{
    __shared__ SMem sm;
    const int b  = blockIdx.x;
    const int t0 = blockIdx.y * BT;
    const int tid = threadIdx.x;
    const int tx = tid & 15;   // a-dimension group (owns a = tx*4+{0..3} and +64)
    const int ty = tid >> 4;   // t-dimension group (owns t_local = ty*4+{0..3})

    // stage conv weights + x windows
    for (int i = tid; i < FILT * 2 * KSZ; i += 256) sm.conv.cw[i] = cw[i];
    for (int i = tid; i < 2 * (BT + KSZ - 1); i += 256) {
        int c  = i / (BT + KSZ - 1);
        int tt = i - c * (BT + KSZ - 1);
        int tg = t0 + tt - PADW;
        const float* src = c ? pwc : pw;
        sm.conv.x[c][tt] = (tg >= 0 && tg < TT) ? src[b * TT + tg] : 0.f;
    }
    __syncthreads();

    // conv: feats (32 filters x 64 t) into LDS
    for (int idx = tid; idx < FILT * BT; idx += 256) {
        int f = idx >> 6, tl = idx & 63;
        float s = 0.f;
        const float* c0 = &sm.conv.cw[(f * 2 + 0) * KSZ];
        const float* c1 = &sm.conv.cw[(f * 2 + 1) * KSZ];
        #pragma unroll
        for (int k = 0; k < KSZ; ++k)
            s += c0[k] * sm.conv.x[0][tl + k] + c1[k] * sm.conv.x[1][tl + k];
        sm.conv.feat[f][tl] = s;
    }
    __syncthreads();

    // acc init: query[b][a] + loc_proj(feat)
    float acc[4][8];
    #pragma unroll
    for (int j = 0; j < 8; ++j) {
        int a = tx * 4 + (j & 3) + ((j >> 2) << 6);
        float qa = q[b * ATT + a];
        #pragma unroll
        for (int i = 0; i < 4; ++i) acc[i][j] = qa;
    }
    #pragma unroll 4
    for (int f = 0; f < FILT; ++f) {
        float fv[4];
        #pragma unroll
        for (int i = 0; i < 4; ++i) fv[i] = sm.conv.feat[f][ty * 4 + i];
        #pragma unroll
        for (int j = 0; j < 8; ++j) {
            int a = tx * 4 + (j & 3) + ((j >> 2) << 6);
            float w = lpw[a * FILT + f];
            #pragma unroll
            for (int i = 0; i < 4; ++i) acc[i][j] += w * fv[i];
        }
    }

    // keys GEMM: acc += enc_tile @ key_w^T  (K = 512, chunks of 32)
    const float* encb = enc + (size_t)b * TT * ENCD;
    for (int k0 = 0; k0 < ENCD; k0 += KC) {
        __syncthreads();   // prior reads of LDS (feat or previous tiles) done
        // stage enc tile (transposed to [k][t])
        for (int i = tid; i < BT * KC / 4; i += 256) {
            int trow = i >> 3, k4 = i & 7;
            int tg = t0 + trow;
            float4 v4 = make_float4(0.f, 0.f, 0.f, 0.f);
            if (tg < TT) v4 = *(const float4*)&encb[(size_t)tg * ENCD + k0 + k4 * 4];
            int kk = k4 * 4;
            sm.gemm.a[kk + 0][trow] = v4.x;
            sm.gemm.a[kk + 1][trow] = v4.y;
            sm.gemm.a[kk + 2][trow] = v4.z;
            sm.gemm.a[kk + 3][trow] = v4.w;
        }
        // stage key_w tile (transposed to [k][a])
        for (int i = tid; i < ATT * KC / 4; i += 256) {
            int arow = i >> 3, k4 = i & 7;
            float4 v4 = *(const float4*)&kw[arow * ENCD + k0 + k4 * 4];
            int kk = k4 * 4;
            sm.gemm.b[kk + 0][arow] = v4.x;
            sm.gemm.b[kk + 1][arow] = v4.y;
            sm.gemm.b[kk + 2][arow] = v4.z;
            sm.gemm.b[kk + 3][arow] = v4.w;
        }
        __syncthreads();
        #pragma unroll
        for (int k = 0; k < KC; ++k) {
            float av[4], bv[8];
            *(float4*)av      = *(const float4*)&sm.gemm.a[k][ty * 4];
            *(float4*)&bv[0]  = *(const float4*)&sm.gemm.b[k][tx * 4];
            *(float4*)&bv[4]  = *(const float4*)&sm.gemm.b[k][tx * 4 + 64];
            #pragma unroll
            for (int i = 0; i < 4; ++i)
                #pragma unroll
                for (int j = 0; j < 8; ++j)
                    acc[i][j] += av[i] * bv[j];
        }
    }

    // epilogue: energies[t] = sum_a v[a] * tanh(acc)
    float vr[8];
    #pragma unroll
    for (int j = 0; j < 8; ++j) vr[j] = vw[tx * 4 + (j & 3) + ((j >> 2) << 6)];
    float pe[4];
    #pragma unroll
    for (int i = 0; i < 4; ++i) {
        float s = 0.f;
        #pragma unroll
        for (int j = 0; j < 8; ++j) s += vr[j] * tanhf(acc[i][j]);
        pe[i] = s;
    }
    #pragma unroll
    for (int off = 1; off < 16; off <<= 1) {
        #pragma unroll
        for (int i = 0; i < 4; ++i) pe[i] += __shfl_xor(pe[i], off, 64);
    }
    if (tx == 0) {
        #pragma unroll
        for (int i = 0; i < 4; ++i) {
            int t = t0 + ty * 4 + i;
            if (t < TT) energ[b * TT + t] = pe[i];
        }
    }
}

// ---------------- K4: softmax over T per batch row ----------------------------
__global__ __launch_bounds__(256) void k_softmax(const float* __restrict__ energ,
                                                 const unsigned char* __restrict__ mask,
                                                 float* __restrict__ wout) {
    int b = blockIdx.x, tid = threadIdx.x;
    __shared__ float sred[8];
    const float* eb = energ + b * TT;
    const unsigned char* mb = mask + b * TT;
    float m = -INFINITY;
    for (int t = tid; t < TT; t += 256) {
        float e = mb[t] ? -INFINITY : eb[t];
        m = fmaxf(m, e);
    }
    #pragma unroll
    for (int off = 32; off; off >>= 1) m = fmaxf(m, __shfl_xor(m, off, 64));
    if ((tid & 63) == 0) sred[tid >> 6] = m;
    __syncthreads();
    m = fmaxf(fmaxf(sred[0], sred[1]), fmaxf(sred[2], sred[3]));
    float s = 0.f;
    for (int t = tid; t < TT; t += 256) {
        float e = mb[t] ? -INFINITY : eb[t];
        s += expf(e - m);
    }
    #pragma unroll
    for (int off = 32; off; off >>= 1) s += __shfl_xor(s, off, 64);
    if ((tid & 63) == 0) sred[4 + (tid >> 6)] = s;
    __syncthreads();
    s = sred[4] + sred[5] + sred[6] + sred[7];
    float inv = 1.f / s;
    float* wb = wout + b * TT;
    for (int t = tid; t < TT; t += 256) {
        float e = mb[t] ? -INFINITY : eb[t];
        wb[t] = expf(e - m) * inv;
    }
}

// ---------------- K5: partial context (8 t-chunks of 125) ---------------------
#define TCH 125
__global__ __launch_bounds__(512) void k_ctx_partial(const float* __restrict__ enc,
                                                     const float* __restrict__ w,
                                                     float* __restrict__ partial) {
    int b = blockIdx.x, c = blockIdx.y;
    int e = threadIdx.x;
    __shared__ float sw[TCH];
    int tstart = c * TCH;
    if (threadIdx.x < TCH) sw[threadIdx.x] = w[b * TT + tstart + threadIdx.x];
    __syncthreads();
    const float* p = enc + ((size_t)b * TT + tstart) * ENCD + e;
    float acc = 0.f;
    #pragma unroll 5
    for (int t = 0; t < TCH; ++t)
        acc += sw[t] * p[(size_t)t * ENCD];
    partial[((b << 3) + c) * ENCD + e] = acc;
}

// ---------------- K6: reduce partials -> context ------------------------------
__global__ __launch_bounds__(512) void k_ctx_reduce(const float* __restrict__ partial,
                                                    float* __restrict__ ctx) {
    int b = blockIdx.x, e = threadIdx.x;
    float s = 0.f;
    #pragma unroll
    for (int c = 0; c < 8; ++c) s += partial[((b << 3) + c) * ENCD + e];
    ctx[b * ENCD + e] = s;
}

// ---------------- launcher ----------------------------------------------------
extern "C" void kernel_launch(void* const* d_in, const int* in_sizes, int n_in,
                              void* d_out, int out_size, void* d_ws, size_t ws_size,
                              hipStream_t stream) {
    const float* dh   = (const float*)d_in[0];
    const float* enc  = (const float*)d_in[1];
    const float* pw   = (const float*)d_in[2];
    const float* pwc  = (const float*)d_in[3];
    const unsigned char* mask = (const unsigned char*)d_in[4];  // bool array, all-false in this problem
    const float* cw   = (const float*)d_in[5];
    const float* lpw  = (const float*)d_in[6];
    const float* qw   = (const float*)d_in[7];
    const float* kw   = (const float*)d_in[8];
    const float* vw   = (const float*)d_in[9];

    float* out_ctx = (float*)d_out;                 // (64, 512)
    float* out_w   = out_ctx + BB * ENCD;           // (64, 1000)

    float* wsf   = (float*)d_ws;
    float* q     = wsf;                              // 64*128
    float* energ = wsf + 8192;                       // 64*1000
    float* part  = wsf + 8192 + 64000;               // 64*8*512

    k_query   <<<dim3(BB),     dim3(128), 0, stream>>>(dh, qw, q);
    k_energies<<<dim3(BB, 16), dim3(256), 0, stream>>>(enc, pw, pwc, cw, lpw, kw, vw, q, energ);
    k_softmax <<<dim3(BB),     dim3(256), 0, stream>>>(energ, mask, out_w);
    k_ctx_partial<<<dim3(BB, 8), dim3(512), 0, stream>>>(enc, out_w, part);
    k_ctx_reduce <<<dim3(BB),    dim3(512), 0, stream>>>(part, out_ctx);
}

// Round 3
// 131.340 us; speedup vs baseline: 2.2431x; 2.2431x over previous
//
#include <hip/hip_runtime.h>
#include <hip/hip_bf16.h>
#include <math.h>

#define BB   64
#define TT   1000
#define DEC  1024
#define ENCD 512
#define ATT  128
#define FILT 32
#define KSZ  31
#define PADW 15
#define BT   64    // t-tile per block
#define KC   64    // K chunk (bf16)
#define KTOT 576   // 512 enc + 32 feat + 32 pad

typedef __attribute__((ext_vector_type(8))) short bf16x8;
typedef __attribute__((ext_vector_type(4))) float f32x4;

static __device__ __forceinline__ ushort f2bf(float f) {
    union { float f; unsigned u; } v; v.f = f;
    unsigned r = (v.u + 0x7FFFu + ((v.u >> 16) & 1u)) >> 16;   // RNE
    return (ushort)r;
}

// ---------------- K0: pack [key_w | loc_proj_w | 0] as bf16 [128][576] --------
__global__ __launch_bounds__(576) void k_prep(const float* __restrict__ kw,
                                              const float* __restrict__ lpw,
                                              ushort* __restrict__ kwb) {
    int a = blockIdx.x, k = threadIdx.x;
    float v = 0.f;
    if (k < ENCD)             v = kw[a * ENCD + k];
    else if (k < ENCD + FILT) v = lpw[a * FILT + (k - ENCD)];
    kwb[a * KTOT + k] = f2bf(v);
}

// ---------------- K1: query = decoder_hidden @ query_w^T  (64 x 128) ----------
__global__ __launch_bounds__(128) void k_query(const float* __restrict__ dh,
                                               const float* __restrict__ qw,
                                               float* __restrict__ q) {
    int b = blockIdx.x, a = threadIdx.x;
    const float* dhb = dh + b * DEC;
    const float* qwa = qw + a * DEC;
    float s = 0.f;
    #pragma unroll 4
    for (int k = 0; k < DEC; k += 4) {
        float4 x = *(const float4*)&dhb[k];
        float4 w = *(const float4*)&qwa[k];
        s += x.x * w.x + x.y * w.y + x.z * w.z + x.w * w.w;
    }
    q[b * ATT + a] = s;
}

// ---------------- K3: fused conv + MFMA GEMM + tanh + v-dot -------------------
// LDS tiles XOR-swizzled at 16B-slot granularity: byte = row*128 + ((slot ^ (row&7))<<4)
union SMemE {
    struct { float x[2][BT + KSZ - 1]; float cw[FILT * 2 * KSZ]; } conv;  // 8.7 KB
    struct { ushort A[BT * KC]; ushort B[ATT * KC]; } g;                  // 8 + 16 KB
};

__global__ __launch_bounds__(256) void k_energies(
    const float* __restrict__ enc, const float* __restrict__ pw,
    const float* __restrict__ pwc, const float* __restrict__ cwg,
    const ushort* __restrict__ kwb, const float* __restrict__ vw,
    const float* __restrict__ q, float* __restrict__ energ)
{
    __shared__ SMemE sm;
    __shared__ __align__(16) ushort featb[BT * KC];   // feat A-tile, logical slots 0..3

    const int b   = blockIdx.x;
    const int t0  = blockIdx.y * BT;
    const int tid = threadIdx.x;
    const int w   = tid >> 6;
    const int l   = tid & 63;

    // ---- phase 0: conv -> featb (bf16, swizzled) ----
    for (int i = tid; i < FILT * 2 * KSZ; i += 256) sm.conv.cw[i] = cwg[i];
    for (int i = tid; i < 2 * (BT + KSZ - 1); i += 256) {
        int c  = i / (BT + KSZ - 1);
        int tt = i - c * (BT + KSZ - 1);
        int tg = t0 + tt - PADW;
        const float* src = c ? pwc : pw;
        sm.conv.x[c][tt] = (tg >= 0 && tg < TT) ? src[b * TT + tg] : 0.f;
    }
    __syncthreads();
    for (int idx = tid; idx < FILT * BT; idx += 256) {
        int f = idx >> 6, tl = idx & 63;
        float s = 0.f;
        const float* c0 = &sm.conv.cw[(f * 2 + 0) * KSZ];
        const float* c1 = &sm.conv.cw[(f * 2 + 1) * KSZ];
        #pragma unroll
        for (int k = 0; k < KSZ; ++k)
            s += c0[k] * sm.conv.x[0][tl + k] + c1[k] * sm.conv.x[1][tl + k];
        int byte = tl * 128 + ((((f >> 3) ^ (tl & 7)) << 4)) + (f & 7) * 2;
        *(ushort*)((char*)featb + byte) = f2bf(s);
    }
    __syncthreads();   // conv region free; featb ready

    // ---- MFMA K-loop: wave w owns t-rows [w*16, w*16+16), ALL 128 a-cols ----
    const int rbase = w * 16;
    f32x4 acc[8];
    #pragma unroll
    for (int n = 0; n < 8; ++n) acc[n] = (f32x4){0.f, 0.f, 0.f, 0.f};

    const float* encb = enc + (size_t)b * TT * ENCD;

    for (int c = 0; c < 9; ++c) {
        // stage A (enc chunk, f32->bf16) unless feat chunk
        if (c < 8) {
            int row = tid >> 2, kq = (tid & 3) * 16;
            int tg  = t0 + row;
            float4 v0, v1, v2, v3;
            if (tg < TT) {
                const float4* p = (const float4*)(encb + (size_t)tg * ENCD + c * KC + kq);
                v0 = p[0]; v1 = p[1]; v2 = p[2]; v3 = p[3];
            } else {
                v0 = v1 = v2 = v3 = make_float4(0.f, 0.f, 0.f, 0.f);
            }
            ushort u[16];
            u[0]=f2bf(v0.x); u[1]=f2bf(v0.y); u[2]=f2bf(v0.z); u[3]=f2bf(v0.w);
            u[4]=f2bf(v1.x); u[5]=f2bf(v1.y); u[6]=f2bf(v1.z); u[7]=f2bf(v1.w);
            u[8]=f2bf(v2.x); u[9]=f2bf(v2.y); u[10]=f2bf(v2.z); u[11]=f2bf(v2.w);
            u[12]=f2bf(v3.x); u[13]=f2bf(v3.y); u[14]=f2bf(v3.z); u[15]=f2bf(v3.w);
            #pragma unroll
            for (int h = 0; h < 2; ++h) {
                int slot = kq / 8 + h;
                int byte = row * 128 + (((slot ^ (row & 7)) << 4));
                *(uint4*)((char*)sm.g.A + byte) = *(const uint4*)&u[h * 8];
            }
        }
        // stage B (kwb chunk)
        {
            int arow = tid >> 1, kh = (tid & 1) * 32;
            const uint4* p = (const uint4*)(kwb + (size_t)arow * KTOT + c * KC + kh);
            #pragma unroll
            for (int h = 0; h < 4; ++h) {
                uint4 v = p[h];
                int slot = kh / 8 + h;
                int byte = arow * 128 + (((slot ^ (arow & 7)) << 4));
                *(uint4*)((char*)sm.g.B + byte) = v;
            }
        }
        __syncthreads();

        const char* Abase = (c < 8) ? (const char*)sm.g.A : (const char*)featb;
        int nks = (c == 8) ? 1 : 2;
        for (int ks = 0; ks < nks; ++ks) {
            int slot = ks * 4 + (l >> 4);
            int row  = rbase + (l & 15);
            bf16x8 af = *(const bf16x8*)(Abase + row * 128 + (((slot ^ (row & 7)) << 4)));
            bf16x8 bfv[8];
            #pragma unroll
            for (int n = 0; n < 8; ++n) {
                int arow = n * 16 + (l & 15);
                bfv[n] = *(const bf16x8*)((const char*)sm.g.B + arow * 128 + (((slot ^ (arow & 7)) << 4)));
            }
            #pragma unroll
            for (int n = 0; n < 8; ++n)
                acc[n] = __builtin_amdgcn_mfma_f32_16x16x32_bf16(af, bfv[n], acc[n], 0, 0, 0);
        }
        __syncthreads();
    }

    // ---- epilogue: + query, tanh, v-dot, reduce over full a (16 lanes) ----
    const float* qb = q + b * ATT;
    float vv[8], qv[8];
    #pragma unroll
    for (int n = 0; n < 8; ++n) {
        int a = n * 16 + (l & 15);
        vv[n] = vw[a];
        qv[n] = qb[a];
    }
    float pe[4];
    #pragma unroll
    for (int r = 0; r < 4; ++r) {
        float s = 0.f;
        #pragma unroll
        for (int n = 0; n < 8; ++n)
            s += vv[n] * tanhf(acc[n][r] + qv[n]);
        pe[r] = s;
    }
    #pragma unroll
    for (int m = 1; m < 16; m <<= 1) {
        #pragma unroll
        for (int r = 0; r < 4; ++r)
            pe[r] += __shfl_xor(pe[r], m, 64);
    }
    if ((l & 15) == 0) {
        int g = l >> 4;
        #pragma unroll
        for (int r = 0; r < 4; ++r) {
            int t = t0 + rbase + g * 4 + r;
            if (t < TT) energ[b * TT + t] = pe[r];
        }
    }
}

// ---------------- K4: softmax over T per batch row ----------------------------
__global__ __launch_bounds__(256) void k_softmax(const float* __restrict__ energ,
                                                 const unsigned char* __restrict__ mask,
                                                 float* __restrict__ wout) {
    int b = blockIdx.x, tid = threadIdx.x;
    __shared__ float sred[8];
    const float* eb = energ + b * TT;
    const unsigned char* mb = mask + b * TT;
    float m = -INFINITY;
    for (int t = tid; t < TT; t += 256) {
        float e = mb[t] ? -INFINITY : eb[t];
        m = fmaxf(m, e);
    }
    #pragma unroll
    for (int off = 32; off; off >>= 1) m = fmaxf(m, __shfl_xor(m, off, 64));
    if ((tid & 63) == 0) sred[tid >> 6] = m;
    __syncthreads();
    m = fmaxf(fmaxf(sred[0], sred[1]), fmaxf(sred[2], sred[3]));
    float s = 0.f;
    for (int t = tid; t < TT; t += 256) {
        float e = mb[t] ? -INFINITY : eb[t];
        s += expf(e - m);
    }
    #pragma unroll
    for (int off = 32; off; off >>= 1) s += __shfl_xor(s, off, 64);
    if ((tid & 63) == 0) sred[4 + (tid >> 6)] = s;
    __syncthreads();
    s = sred[4] + sred[5] + sred[6] + sred[7];
    float inv = 1.f / s;
    float* wb = wout + b * TT;
    for (int t = tid; t < TT; t += 256) {
        float e = mb[t] ? -INFINITY : eb[t];
        wb[t] = expf(e - m) * inv;
    }
}

// ---------------- K5: partial context (8 t-chunks of 125) ---------------------
#define TCH 125
__global__ __launch_bounds__(512) void k_ctx_partial(const float* __restrict__ enc,
                                                     const float* __restrict__ w,
                                                     float* __restrict__ partial) {
    int b = blockIdx.x, c = blockIdx.y;
    int e = threadIdx.x;
    __shared__ float sw[TCH];
    int tstart = c * TCH;
    if (threadIdx.x < TCH) sw[threadIdx.x] = w[b * TT + tstart + threadIdx.x];
    __syncthreads();
    const float* p = enc + ((size_t)b * TT + tstart) * ENCD + e;
    float acc = 0.f;
    #pragma unroll 5
    for (int t = 0; t < TCH; ++t)
        acc += sw[t] * p[(size_t)t * ENCD];
    partial[((b << 3) + c) * ENCD + e] = acc;
}

// ---------------- K6: reduce partials -> context ------------------------------
__global__ __launch_bounds__(512) void k_ctx_reduce(const float* __restrict__ partial,
                                                    float* __restrict__ ctx) {
    int b = blockIdx.x, e = threadIdx.x;
    float s = 0.f;
    #pragma unroll
    for (int c = 0; c < 8; ++c) s += partial[((b << 3) + c) * ENCD + e];
    ctx[b * ENCD + e] = s;
}

// ---------------- launcher ----------------------------------------------------
extern "C" void kernel_launch(void* const* d_in, const int* in_sizes, int n_in,
                              void* d_out, int out_size, void* d_ws, size_t ws_size,
                              hipStream_t stream) {
    const float* dh   = (const float*)d_in[0];
    const float* enc  = (const float*)d_in[1];
    const float* pw   = (const float*)d_in[2];
    const float* pwc  = (const float*)d_in[3];
    const unsigned char* mask = (const unsigned char*)d_in[4];
    const float* cw   = (const float*)d_in[5];
    const float* lpw  = (const float*)d_in[6];
    const float* qw   = (const float*)d_in[7];
    const float* kw   = (const float*)d_in[8];
    const float* vw   = (const float*)d_in[9];

    float* out_ctx = (float*)d_out;                 // (64, 512)
    float* out_w   = out_ctx + BB * ENCD;           // (64, 1000)

    float* wsf   = (float*)d_ws;
    float*  q     = wsf;                             // 8192 f
    float*  energ = wsf + 8192;                      // 64000 f
    float*  part  = wsf + 8192 + 64000;              // 32768 f
    ushort* kwb   = (ushort*)(wsf + 8192 + 64000 + 32768);  // 128*576 bf16

    k_prep    <<<dim3(ATT),    dim3(KTOT), 0, stream>>>(kw, lpw, kwb);
    k_query   <<<dim3(BB),     dim3(128),  0, stream>>>(dh, qw, q);
    k_energies<<<dim3(BB, 16), dim3(256),  0, stream>>>(enc, pw, pwc, cw, kwb, vw, q, energ);
    k_softmax <<<dim3(BB),     dim3(256),  0, stream>>>(energ, mask, out_w);
    k_ctx_partial<<<dim3(BB, 8), dim3(512), 0, stream>>>(enc, out_w, part);
    k_ctx_reduce <<<dim3(BB),    dim3(512), 0, stream>>>(part, out_ctx);
}

// Round 4
// 114.125 us; speedup vs baseline: 2.5814x; 1.1508x over previous
//
#include <hip/hip_runtime.h>
#include <hip/hip_bf16.h>
#include <math.h>

#define BB   64
#define TT   1000
#define DEC  1024
#define ENCD 512
#define ATT  128
#define FILT 32
#define KSZ  31
#define PADW 15
#define BT   64    // t-tile per block
#define KC   64    // K chunk (bf16)

typedef __attribute__((ext_vector_type(8))) short bf16x8;
typedef __attribute__((ext_vector_type(4))) float f32x4;

static __device__ __forceinline__ ushort f2bf(float f) {
    union { float f; unsigned u; } v; v.f = f;
    unsigned r = (v.u + 0x7FFFu + ((v.u >> 16) & 1u)) >> 16;   // RNE
    return (ushort)r;
}

// ---------------- K0: pack B into fragment-major bf16 layout ------------------
// element index = (((c*2+ks)*8 + n)*64 + lane)*8 + j
//   maps to  a = n*16 + (lane&15),  k = c*64 + ks*32 + (lane>>4)*8 + j
//   k<512: key_w[a][k];  512<=k<544: loc_proj_w[a][k-512];  else 0
__global__ __launch_bounds__(256) void k_prep(const float* __restrict__ kw,
                                              const float* __restrict__ lpw,
                                              ushort* __restrict__ kwbF) {
    int idx = blockIdx.x * 256 + threadIdx.x;     // 0..9215
    int l  = idx & 63;
    int n  = (idx >> 6) & 7;
    int ks = (idx >> 9) & 1;
    int c  = idx >> 10;
    if (c >= 9) return;
    int a  = n * 16 + (l & 15);
    int k0 = c * 64 + ks * 32 + (l >> 4) * 8;
    ushort u[8];
    #pragma unroll
    for (int j = 0; j < 8; ++j) {
        int k = k0 + j;
        float v = 0.f;
        if (k < ENCD)             v = kw[a * ENCD + k];
        else if (k < ENCD + FILT) v = lpw[a * FILT + (k - ENCD)];
        u[j] = f2bf(v);
    }
    *(uint4*)&kwbF[(size_t)idx * 8] = *(const uint4*)u;
}

// ---------------- K1: query = decoder_hidden @ query_w^T  (64 x 128) ----------
__global__ __launch_bounds__(128) void k_query(const float* __restrict__ dh,
                                               const float* __restrict__ qw,
                                               float* __restrict__ q) {
    int b = blockIdx.x, a = threadIdx.x;
    const float* dhb = dh + b * DEC;
    const float* qwa = qw + a * DEC;
    float s = 0.f;
    #pragma unroll 4
    for (int k = 0; k < DEC; k += 4) {
        float4 x = *(const float4*)&dhb[k];
        float4 w = *(const float4*)&qwa[k];
        s += x.x * w.x + x.y * w.y + x.z * w.z + x.w * w.w;
    }
    q[b * ATT + a] = s;
}

// ---------------- K3: fused conv + barrier-free MFMA GEMM + tanh + v-dot ------
__global__ __launch_bounds__(256) void k_energies(
    const float* __restrict__ enc, const float* __restrict__ pw,
    const float* __restrict__ pwc, const float* __restrict__ cwg,
    const ushort* __restrict__ kwbF, const float* __restrict__ vw,
    const float* __restrict__ q, float* __restrict__ energ)
{
    __shared__ struct { float x[2][BT + KSZ - 1]; float cw[FILT * 2 * KSZ]; } conv;
    __shared__ __align__(16) ushort featb[BT * KC];   // slots 0..3 hold 32 filters

    const int b   = blockIdx.x;
    const int t0  = blockIdx.y * BT;
    const int tid = threadIdx.x;
    const int w   = tid >> 6;
    const int l   = tid & 63;

    // ---- conv phase (2 barriers, then barrier-free) ----
    for (int i = tid; i < FILT * 2 * KSZ; i += 256) conv.cw[i] = cwg[i];
    for (int i = tid; i < 2 * (BT + KSZ - 1); i += 256) {
        int c  = i / (BT + KSZ - 1);
        int tt = i - c * (BT + KSZ - 1);
        int tg = t0 + tt - PADW;
        const float* src = c ? pwc : pw;
        conv.x[c][tt] = (tg >= 0 && tg < TT) ? src[b * TT + tg] : 0.f;
    }
    __syncthreads();
    for (int idx = tid; idx < FILT * BT; idx += 256) {
        int f = idx >> 6, tl = idx & 63;
        float s = 0.f;
        const float* c0 = &conv.cw[(f * 2 + 0) * KSZ];
        const float* c1 = &conv.cw[(f * 2 + 1) * KSZ];
        #pragma unroll
        for (int k = 0; k < KSZ; ++k)
            s += c0[k] * conv.x[0][tl + k] + c1[k] * conv.x[1][tl + k];
        int byte = tl * 128 + ((((f >> 3) ^ (tl & 7)) << 4)) + (f & 7) * 2;
        *(ushort*)((char*)featb + byte) = f2bf(s);
    }
    __syncthreads();   // featb ready; no more barriers

    // ---- register-resident MFMA K-loop ----
    const int r  = l & 15;         // row within 16
    const int sl = l >> 4;         // k-slot 0..3
    const int row  = w * 16 + r;   // t-row within tile
    const int trow = t0 + row;
    const int trc  = (trow < TT) ? trow : (TT - 1);   // clamped, stores guarded
    const float*  pa = enc + ((size_t)b * TT + trc) * ENCD + sl * 8;
    const ushort* pb = kwbF + (size_t)l * 8;

    f32x4 acc[8];
    #pragma unroll
    for (int n = 0; n < 8; ++n) acc[n] = (f32x4){0.f, 0.f, 0.f, 0.f};

    float4 abuf[2][4];
    {   // prologue: load chunk 0
        const float* p = pa;
        abuf[0][0] = *(const float4*)(p + 0);
        abuf[0][1] = *(const float4*)(p + 4);
        abuf[0][2] = *(const float4*)(p + 32);
        abuf[0][3] = *(const float4*)(p + 36);
    }

    #pragma unroll
    for (int c = 0; c < 9; ++c) {
        const int cur = c & 1, nx = cur ^ 1;
        if (c < 8) {   // prefetch next chunk's A into the other reg set
            const float* p = pa + (c + 1) * KC;
            abuf[nx][0] = *(const float4*)(p + 0);
            abuf[nx][1] = *(const float4*)(p + 4);
            abuf[nx][2] = *(const float4*)(p + 32);
            abuf[nx][3] = *(const float4*)(p + 36);
        }
        const int nks = (c == 8) ? 1 : 2;
        #pragma unroll
        for (int ks = 0; ks < 2; ++ks) {
            if (ks >= nks) break;
            bf16x8 af;
            if (c == 8) {
                af = *(const bf16x8*)((const char*)featb + row * 128 + (((sl ^ (row & 7)) << 4)));
            } else {
                float4 lo = abuf[cur][ks * 2 + 0];
                float4 hi = abuf[cur][ks * 2 + 1];
                ushort u[8];
                u[0] = f2bf(lo.x); u[1] = f2bf(lo.y); u[2] = f2bf(lo.z); u[3] = f2bf(lo.w);
                u[4] = f2bf(hi.x); u[5] = f2bf(hi.y); u[6] = f2bf(hi.z); u[7] = f2bf(hi.w);
                af = *(const bf16x8*)u;
            }
            const ushort* pbc = pb + (size_t)((c * 2 + ks) * 8) * 512;
            bf16x8 bfv[8];
            #pragma unroll
            for (int n = 0; n < 8; ++n)
                bfv[n] = *(const bf16x8*)(pbc + (size_t)n * 512);
            #pragma unroll
            for (int n = 0; n < 8; ++n)
                acc[n] = __builtin_amdgcn_mfma_f32_16x16x32_bf16(af, bfv[n], acc[n], 0, 0, 0);
        }
    }

    // ---- epilogue: + query, tanh, v-dot, reduce over full a (16 lanes) ----
    const float* qb = q + b * ATT;
    float vv[8], qv[8];
    #pragma unroll
    for (int n = 0; n < 8; ++n) {
        int a = n * 16 + r;
        vv[n] = vw[a];
        qv[n] = qb[a];
    }
    float pe[4];
    #pragma unroll
    for (int rr = 0; rr < 4; ++rr) {
        float s = 0.f;
        #pragma unroll
        for (int n = 0; n < 8; ++n)
            s += vv[n] * tanhf(acc[n][rr] + qv[n]);
        pe[rr] = s;
    }
    #pragma unroll
    for (int m = 1; m < 16; m <<= 1) {
        #pragma unroll
        for (int rr = 0; rr < 4; ++rr)
            pe[rr] += __shfl_xor(pe[rr], m, 64);
    }
    if (r == 0) {
        int g = sl;
        #pragma unroll
        for (int rr = 0; rr < 4; ++rr) {
            int t = t0 + w * 16 + g * 4 + rr;
            if (t < TT) energ[b * TT + t] = pe[rr];
        }
    }
}

// ---------------- K4: softmax over T per batch row ----------------------------
__global__ __launch_bounds__(256) void k_softmax(const float* __restrict__ energ,
                                                 const unsigned char* __restrict__ mask,
                                                 float* __restrict__ wout) {
    int b = blockIdx.x, tid = threadIdx.x;
    __shared__ float sred[8];
    const float* eb = energ + b * TT;
    const unsigned char* mb = mask + b * TT;
    float m = -INFINITY;
    for (int t = tid; t < TT; t += 256) {
        float e = mb[t] ? -INFINITY : eb[t];
        m = fmaxf(m, e);
    }
    #pragma unroll
    for (int off = 32; off; off >>= 1) m = fmaxf(m, __shfl_xor(m, off, 64));
    if ((tid & 63) == 0) sred[tid >> 6] = m;
    __syncthreads();
    m = fmaxf(fmaxf(sred[0], sred[1]), fmaxf(sred[2], sred[3]));
    float s = 0.f;
    for (int t = tid; t < TT; t += 256) {
        float e = mb[t] ? -INFINITY : eb[t];
        s += expf(e - m);
    }
    #pragma unroll
    for (int off = 32; off; off >>= 1) s += __shfl_xor(s, off, 64);
    if ((tid & 63) == 0) sred[4 + (tid >> 6)] = s;
    __syncthreads();
    s = sred[4] + sred[5] + sred[6] + sred[7];
    float inv = 1.f / s;
    float* wb = wout + b * TT;
    for (int t = tid; t < TT; t += 256) {
        float e = mb[t] ? -INFINITY : eb[t];
        wb[t] = expf(e - m) * inv;
    }
}

// ---------------- K5: partial context (8 t-chunks of 125) ---------------------
#define TCH 125
__global__ __launch_bounds__(512) void k_ctx_partial(const float* __restrict__ enc,
                                                     const float* __restrict__ w,
                                                     float* __restrict__ partial) {
    int b = blockIdx.x, c = blockIdx.y;
    int e = threadIdx.x;
    __shared__ float sw[TCH];
    int tstart = c * TCH;
    if (threadIdx.x < TCH) sw[threadIdx.x] = w[b * TT + tstart + threadIdx.x];
    __syncthreads();
    const float* p = enc + ((size_t)b * TT + tstart) * ENCD + e;
    float acc = 0.f;
    #pragma unroll 5
    for (int t = 0; t < TCH; ++t)
        acc += sw[t] * p[(size_t)t * ENCD];
    partial[((b << 3) + c) * ENCD + e] = acc;
}

// ---------------- K6: reduce partials -> context ------------------------------
__global__ __launch_bounds__(512) void k_ctx_reduce(const float* __restrict__ partial,
                                                    float* __restrict__ ctx) {
    int b = blockIdx.x, e = threadIdx.x;
    float s = 0.f;
    #pragma unroll
    for (int c = 0; c < 8; ++c) s += partial[((b << 3) + c) * ENCD + e];
    ctx[b * ENCD + e] = s;
}

// ---------------- launcher ----------------------------------------------------
extern "C" void kernel_launch(void* const* d_in, const int* in_sizes, int n_in,
                              void* d_out, int out_size, void* d_ws, size_t ws_size,
                              hipStream_t stream) {
    const float* dh   = (const float*)d_in[0];
    const float* enc  = (const float*)d_in[1];
    const float* pw   = (const float*)d_in[2];
    const float* pwc  = (const float*)d_in[3];
    const unsigned char* mask = (const unsigned char*)d_in[4];
    const float* cw   = (const float*)d_in[5];
    const float* lpw  = (const float*)d_in[6];
    const float* qw   = (const float*)d_in[7];
    const float* kw   = (const float*)d_in[8];
    const float* vw   = (const float*)d_in[9];

    float* out_ctx = (float*)d_out;                 // (64, 512)
    float* out_w   = out_ctx + BB * ENCD;           // (64, 1000)

    float* wsf   = (float*)d_ws;
    float*  q     = wsf;                             // 8192 f
    float*  energ = wsf + 8192;                      // 64000 f
    float*  part  = wsf + 8192 + 64000;              // 32768 f
    ushort* kwbF  = (ushort*)(wsf + 8192 + 64000 + 32768);  // 9*2*8*64*8 = 73728 bf16

    k_prep    <<<dim3(36),     dim3(256), 0, stream>>>(kw, lpw, kwbF);
    k_query   <<<dim3(BB),     dim3(128), 0, stream>>>(dh, qw, q);
    k_energies<<<dim3(BB, 16), dim3(256), 0, stream>>>(enc, pw, pwc, cw, kwbF, vw, q, energ);
    k_softmax <<<dim3(BB),     dim3(256), 0, stream>>>(energ, mask, out_w);
    k_ctx_partial<<<dim3(BB, 8), dim3(512), 0, stream>>>(enc, out_w, part);
    k_ctx_reduce <<<dim3(BB),    dim3(512), 0, stream>>>(part, out_ctx);
}